// Round 9
// baseline (656.830 us; speedup 1.0000x reference)
//
#include <hip/hip_runtime.h>

// ---------------------------------------------------------------------------
// GCN forward, bf16 activations / fp32 accum.
// CSR: bucketed radix (dst>>9) + per-(node, src-slice-of-8) sub-lists (rs8).
// Aggregate: R5 sub-wave uint4 gather structure, but iterated over 8 src
//   slices (3.2MB each -> per-XCD L2 resident) for L2 locality; 1-op converts.
// GEMM1/2: MFMA 32x32x16 bf16, LDS-free, W frags in VGPRs; GEMM1 converts
//   fp32 x in-register (no xprep pass).
// Head: pool(h2) first (linearity), then tiny 64-graph GEMMs.
// ---------------------------------------------------------------------------

typedef __attribute__((ext_vector_type(8))) short bfrag;     // 8 bf16 = 4 VGPR
typedef __attribute__((ext_vector_type(16))) float f32x16;   // MFMA C/D

__device__ __forceinline__ unsigned short f2bf(float f) {
    unsigned int u = __builtin_bit_cast(unsigned int, f);
    u = (u + 0x7FFFu + ((u >> 16) & 1u)) >> 16;
    return (unsigned short)u;
}
__device__ __forceinline__ float bf2f(unsigned int lo16) {
    unsigned int v = lo16 << 16;
    return __builtin_bit_cast(float, v);
}
// 1-op-per-element bf16x2 -> {lo,hi} floats, acc += f * c
__device__ __forceinline__ void macc2(float& aLo, float& aHi, unsigned int d, float c) {
    float lo = __builtin_bit_cast(float, d << 16);
    float hi = __builtin_bit_cast(float, d & 0xFFFF0000u);
    aLo += lo * c;
    aHi += hi * c;
}
__device__ __forceinline__ void macc8(float* acc, const uint4& v, float c) {
    macc2(acc[0], acc[1], v.x, c);
    macc2(acc[2], acc[3], v.y, c);
    macc2(acc[4], acc[5], v.z, c);
    macc2(acc[6], acc[7], v.w, c);
}

// --- A1: bucket histogram (bucket = dst >> 9) ---
__global__ __launch_bounds__(256) void bucket_hist_kernel(const int* __restrict__ dst,
                                                          int* __restrict__ bcount, int E) {
    __shared__ int h[256];
    int t = threadIdx.x;
    h[t] = 0;
    __syncthreads();
    int base = blockIdx.x * 4096;
#pragma unroll
    for (int i = 0; i < 16; ++i) {
        int e = base + t + i * 256;
        if (e < E) atomicAdd(&h[dst[e] >> 9], 1);
    }
    __syncthreads();
    if (h[t] > 0) atomicAdd(&bcount[t], h[t]);
}

__global__ void bucket_scan_kernel(const int* __restrict__ bcount, int* __restrict__ bstart,
                                   int* __restrict__ rs8, int NB, int N, int E) {
    __shared__ int s[256];
    int t = threadIdx.x;
    int v = (t < NB) ? bcount[t] : 0;
    s[t] = v;
    __syncthreads();
    for (int off = 1; off < 256; off <<= 1) {
        int tmp = 0;
        if (t >= off) tmp = s[t - off];
        __syncthreads();
        s[t] += tmp;
        __syncthreads();
    }
    bstart[t] = s[t] - v;
    if (t == 255) bstart[256] = s[255];
    if (t == 0) rs8[(size_t)N * 8] = E;   // global end sentinel
}

// --- A2: stage packed (src | local_dst<<17) into bucket windows ---
__global__ __launch_bounds__(256) void bucket_scatter_kernel(const int* __restrict__ src,
                                                             const int* __restrict__ dst,
                                                             const int* __restrict__ bstart,
                                                             int* __restrict__ bfill,
                                                             unsigned int* __restrict__ stage,
                                                             int E) {
    __shared__ int hist[256];
    __shared__ int abase[256];
    int t = threadIdx.x;
    hist[t] = 0;
    __syncthreads();
    int base = blockIdx.x * 4096;
#pragma unroll
    for (int i = 0; i < 16; ++i) {
        int e = base + t + i * 256;
        if (e < E) atomicAdd(&hist[dst[e] >> 9], 1);
    }
    __syncthreads();
    if (hist[t] > 0) {
        int r = atomicAdd(&bfill[t], hist[t]);
        abase[t] = bstart[t] + r;
    }
    __syncthreads();
    hist[t] = 0;
    __syncthreads();
#pragma unroll
    for (int i = 0; i < 16; ++i) {
        int e = base + t + i * 256;
        if (e < E) {
            int d = dst[e];
            int b = d >> 9;
            int slot = atomicAdd(&hist[b], 1);
            stage[abase[b] + slot] = (unsigned)src[e] | ((unsigned)(d & 511) << 17);
        }
    }
}

// --- B: per-bucket CSR finalize with per-(node, src-slice-of-8) sub-lists ---
__global__ __launch_bounds__(256) void csr_build_kernel(const unsigned int* __restrict__ stage,
                                                        const int* __restrict__ bstart,
                                                        int* __restrict__ rs8,
                                                        float* __restrict__ dis,
                                                        int* __restrict__ csr_src, int N) {
    __shared__ int cnt[4096];   // (node local 512) x (src slice 8)
    __shared__ int psum[256];
    int b = blockIdx.x, t = threadIdx.x;
    int node0 = b << 9;
#pragma unroll
    for (int q = 0; q < 16; ++q) cnt[t + q * 256] = 0;
    __syncthreads();
    int eb = bstart[b], ee = bstart[b + 1];
    for (int e = eb + t; e < ee; e += 256) {
        unsigned w = stage[e];
        int l = w >> 17;
        int s = (int)(w & 0x1FFFFu);
        int sb = (int)(((unsigned long long)(unsigned)s * 8u) / (unsigned)N);
        atomicAdd(&cnt[l * 8 + sb], 1);
    }
    __syncthreads();
    int loc[16];
    int run = 0;
#pragma unroll
    for (int k = 0; k < 16; ++k) { loc[k] = run; run += cnt[16 * t + k]; }
    psum[t] = run;
    __syncthreads();
    for (int off = 1; off < 256; off <<= 1) {
        int tmp = 0;
        if (t >= off) tmp = psum[t - off];
        __syncthreads();
        psum[t] += tmp;
        __syncthreads();
    }
    int base = psum[t] - run;
    int dega = loc[8];
    int degb = run - loc[8];
#pragma unroll
    for (int k = 0; k < 16; ++k) cnt[16 * t + k] = base + loc[k];
    int na = node0 + 2 * t, nb2 = na + 1;
    if (na < N) {
        dis[na] = rsqrtf(1.f + (float)dega);
#pragma unroll
        for (int k = 0; k < 8; ++k) rs8[(size_t)na * 8 + k] = eb + base + loc[k];
    }
    if (nb2 < N) {
        dis[nb2] = rsqrtf(1.f + (float)degb);
#pragma unroll
        for (int k = 0; k < 8; ++k) rs8[(size_t)nb2 * 8 + k] = eb + base + loc[8 + k];
    }
    __syncthreads();
    for (int e = eb + t; e < ee; e += 256) {
        unsigned w = stage[e];
        int l = w >> 17;
        int s = (int)(w & 0x1FFFFu);
        int sb = (int)(((unsigned long long)(unsigned)s * 8u) / (unsigned)N);
        int slot = atomicAdd(&cnt[l * 8 + sb], 1);
        csr_src[eb + slot] = s;
    }
}

// --- pack W[K][NC] fp32 -> bf16 MFMA B-frag order ---
template <int K, int NC>
__global__ __launch_bounds__(256) void wprep_kernel(const float* __restrict__ W,
                                                    unsigned short* __restrict__ Wf) {
    constexpr int CT = NC / 32, KT = K / 16;
    int idx = blockIdx.x * blockDim.x + threadIdx.x;
    if (idx >= KT * CT * 64) return;
    int l = idx & 63;
    int fi = idx >> 6;
    int ct = fi % CT, kt = fi / CT;
    int n = ct * 32 + (l & 31);
    int k0 = kt * 16 + 8 * (l >> 5);
    unsigned short v[8];
#pragma unroll
    for (int j = 0; j < 8; ++j) v[j] = f2bf(W[(size_t)(k0 + j) * NC + n]);
    uint4 o;
    o.x = (unsigned)v[0] | ((unsigned)v[1] << 16);
    o.y = (unsigned)v[2] | ((unsigned)v[3] << 16);
    o.z = (unsigned)v[4] | ((unsigned)v[5] << 16);
    o.w = (unsigned)v[6] | ((unsigned)v[7] << 16);
    *(uint4*)&Wf[(size_t)idx * 8] = o;
}

// --- MFMA GEMM: C[M][NC](bf16) = A[M][K] @ Wf(frag-packed bf16) ---
//     One wave per 32-row tile. A fp32 (converted in-reg) or bf16.
template <int K, int NC, bool IN_F32>
__global__ __launch_bounds__(256) void gemm_mfma_kernel(const void* __restrict__ Av,
                                                        const unsigned short* __restrict__ Wf,
                                                        unsigned short* __restrict__ C,
                                                        int M) {
    constexpr int KT = K / 16, CT = NC / 32;
    int wid = (blockIdx.x * blockDim.x + threadIdx.x) >> 6;
    int lane = threadIdx.x & 63;
    int row0 = wid * 32;
    if (row0 >= M) return;

    bfrag B[KT][CT];
#pragma unroll
    for (int kt = 0; kt < KT; ++kt)
#pragma unroll
        for (int ct = 0; ct < CT; ++ct)
            B[kt][ct] = *(const bfrag*)&Wf[(size_t)((kt * CT + ct) * 64 + lane) * 8];

    f32x16 acc[CT];
#pragma unroll
    for (int ct = 0; ct < CT; ++ct)
#pragma unroll
        for (int i = 0; i < 16; ++i) acc[ct][i] = 0.f;

    int r = row0 + (lane & 31);
    if (r >= M) r = M - 1;
#pragma unroll
    for (int kt = 0; kt < KT; ++kt) {
        bfrag a;
        if (IN_F32) {
            const float* Arow = &((const float*)Av)[(size_t)r * K + 8 * (lane >> 5)];
            float4 v0 = *(const float4*)&Arow[kt * 16];
            float4 v1 = *(const float4*)&Arow[kt * 16 + 4];
            a[0] = (short)f2bf(v0.x); a[1] = (short)f2bf(v0.y);
            a[2] = (short)f2bf(v0.z); a[3] = (short)f2bf(v0.w);
            a[4] = (short)f2bf(v1.x); a[5] = (short)f2bf(v1.y);
            a[6] = (short)f2bf(v1.z); a[7] = (short)f2bf(v1.w);
        } else {
            const unsigned short* Arow =
                &((const unsigned short*)Av)[(size_t)r * K + 8 * (lane >> 5)];
            a = *(const bfrag*)&Arow[kt * 16];
        }
#pragma unroll
        for (int ct = 0; ct < CT; ++ct)
            acc[ct] = __builtin_amdgcn_mfma_f32_32x32x16_bf16(a, B[kt][ct], acc[ct], 0, 0, 0);
    }

    // C/D layout: col = lane&31, row = (reg&3) + 8*(reg>>2) + 4*(lane>>5)
    int colb = lane & 31;
    int rowq = 4 * (lane >> 5);
#pragma unroll
    for (int ct = 0; ct < CT; ++ct) {
        int col = ct * 32 + colb;
#pragma unroll
        for (int rg = 0; rg < 16; ++rg) {
            int row = row0 + (rg & 3) + 8 * (rg >> 2) + rowq;
            if (row < M) C[(size_t)row * NC + col] = f2bf(acc[ct][rg]);
        }
    }
}

// --- wave-per-node bf16 gather aggregation over 8 src slices (fp32 accum) ---
template <int NC>
__global__ __launch_bounds__(256) void aggregate_kernel(const unsigned short* __restrict__ h,
                                                        const float* __restrict__ dis,
                                                        const int* __restrict__ rs8,
                                                        const int* __restrict__ csr_src,
                                                        const float* __restrict__ bias,
                                                        unsigned short* __restrict__ out,
                                                        int N) {
    constexpr int LPR = NC / 8;   // lanes per row (16B = 8 bf16 each)
    constexpr int RPS = 64 / LPR; // rows (edges) per step
    int wid = (blockIdx.x * blockDim.x + threadIdx.x) >> 6;
    int lane = threadIdx.x & 63;
    if (wid >= N) return;
    int n = wid;
    int sub = lane / LPR;
    int fid = lane % LPR;
    const uint4* h4 = (const uint4*)h;
    float d = dis[n];
    float acc[8];
#pragma unroll
    for (int i = 0; i < 8; ++i) acc[i] = 0.f;
    if (sub == 0) {
        uint4 hv = h4[(size_t)n * LPR + fid];
        macc8(acc, hv, d);
    }

    // 8 passes over src slices; slice p's rows (~3.2MB of h) stay hot in L2
    for (int p = 0; p < 8; ++p) {
        int beg = rs8[(size_t)n * 8 + p];
        int end = rs8[(size_t)n * 8 + p + 1];
        for (int e0 = beg; e0 < end; e0 += 64) {
            int idx = e0 + lane;
            int sv = 0;
            float dv = 0.f;
            if (idx < end) { sv = csr_src[idx]; dv = dis[sv]; }
            int cnt = min(64, end - e0);
            int j = 0;
            for (; j + 2 * RPS <= cnt; j += 2 * RPS) {
                int ja = j + sub, jb = j + RPS + sub;
                int sa = __shfl(sv, ja); float ca = __shfl(dv, ja);
                int sb = __shfl(sv, jb); float cb = __shfl(dv, jb);
                uint4 va = h4[(size_t)sa * LPR + fid];
                uint4 vb = h4[(size_t)sb * LPR + fid];
                macc8(acc, va, ca);
                macc8(acc, vb, cb);
            }
            for (; j < cnt; j += RPS) {
                int jj = j + sub;
                int jc = min(jj, cnt - 1);   // dupes clamp to same row -> coalesced
                int s = __shfl(sv, jc);
                float c = __shfl(dv, jc);
                if (jj >= cnt) c = 0.f;
                uint4 v = h4[(size_t)s * LPR + fid];
                macc8(acc, v, c);
            }
        }
    }
#pragma unroll
    for (int m = LPR; m < 64; m <<= 1) {
#pragma unroll
        for (int i = 0; i < 8; ++i) acc[i] += __shfl_xor(acc[i], m);
    }
    if (sub == 0) {
        const float4 bv0 = *(const float4*)&bias[fid * 8 + 0];
        const float4 bv1 = *(const float4*)&bias[fid * 8 + 4];
        float r[8];
        r[0] = fmaxf(acc[0] * d + bv0.x, 0.f);
        r[1] = fmaxf(acc[1] * d + bv0.y, 0.f);
        r[2] = fmaxf(acc[2] * d + bv0.z, 0.f);
        r[3] = fmaxf(acc[3] * d + bv0.w, 0.f);
        r[4] = fmaxf(acc[4] * d + bv1.x, 0.f);
        r[5] = fmaxf(acc[5] * d + bv1.y, 0.f);
        r[6] = fmaxf(acc[6] * d + bv1.z, 0.f);
        r[7] = fmaxf(acc[7] * d + bv1.w, 0.f);
        uint4 o;
        o.x = (unsigned)f2bf(r[0]) | ((unsigned)f2bf(r[1]) << 16);
        o.y = (unsigned)f2bf(r[2]) | ((unsigned)f2bf(r[3]) << 16);
        o.z = (unsigned)f2bf(r[4]) | ((unsigned)f2bf(r[5]) << 16);
        o.w = (unsigned)f2bf(r[6]) | ((unsigned)f2bf(r[7]) << 16);
        *(uint4*)&out[(size_t)n * NC + fid * 8] = o;
    }
}

// --- pool h2 (bf16, N x 64) -> gsum[64 x 64] (batch sorted) ---
__global__ __launch_bounds__(64) void pool_kernel(const unsigned short* __restrict__ h2,
                                                  const int* __restrict__ batch,
                                                  float* __restrict__ gsum, int N) {
    int f = threadIdx.x;
    int n0 = blockIdx.x * 128;
    int nend = min(n0 + 128, N);
    float acc = 0.f;
    int gcur = batch[n0];
    for (int n = n0; n < nend; ++n) {
        int g = batch[n];
        if (g != gcur) {
            atomicAdd(&gsum[gcur * 64 + f], acc);
            acc = 0.f;
            gcur = g;
        }
        acc += bf2f(h2[(size_t)n * 64 + f]);
    }
    atomicAdd(&gsum[gcur * 64 + f], acc);
}

__global__ __launch_bounds__(256) void count_batch_kernel(const int* __restrict__ batch,
                                                          int* __restrict__ gcnt, int N) {
    __shared__ int lc[64];
    int t = threadIdx.x;
    if (t < 64) lc[t] = 0;
    __syncthreads();
    int n = blockIdx.x * blockDim.x + t;
    if (n < N) atomicAdd(&lc[batch[n]], 1);
    __syncthreads();
    if (t < 64 && lc[t] > 0) atomicAdd(&gcnt[t], lc[t]);
}

// --- head: ge = pooled_h2 @ Wf1 + bf1 ; ic = ge @ Wf2 + bf2 ---
__global__ __launch_bounds__(128) void head_kernel(const float* __restrict__ gsum,
                                                   const int* __restrict__ gcnt,
                                                   const float* __restrict__ Wf1,
                                                   const float* __restrict__ bf1,
                                                   const float* __restrict__ Wf2,
                                                   const float* __restrict__ bf2,
                                                   float* __restrict__ out) {
    __shared__ float ph[64];
    __shared__ float red0[128], red1[128];
    int g = blockIdx.x, f = threadIdx.x;
    if (f < 64) ph[f] = gsum[g * 64 + f] / (float)max(gcnt[g], 1);
    __syncthreads();
    float ge = bf1[f];
#pragma unroll 8
    for (int k = 0; k < 64; ++k) ge += ph[k] * Wf1[k * 128 + f];
    out[g * 128 + f] = ge;
    red0[f] = ge * Wf2[f * 2 + 0];
    red1[f] = ge * Wf2[f * 2 + 1];
    __syncthreads();
    for (int off = 64; off > 0; off >>= 1) {
        if (f < off) { red0[f] += red0[f + off]; red1[f] += red1[f + off]; }
        __syncthreads();
    }
    if (f == 0) {
        out[8192 + 1 + g * 2 + 0] = red0[0] + bf2[0];
        out[8192 + 1 + g * 2 + 1] = red1[0] + bf2[1];
        if (g == 0) out[8192] = 0.f;
    }
}

extern "C" void kernel_launch(void* const* d_in, const int* in_sizes, int n_in,
                              void* d_out, int out_size, void* d_ws, size_t ws_size,
                              hipStream_t stream) {
    const float* x   = (const float*)d_in[0];
    const float* W1  = (const float*)d_in[1];
    const float* b1  = (const float*)d_in[2];
    const float* W2  = (const float*)d_in[3];
    const float* b2  = (const float*)d_in[4];
    const float* Wf1 = (const float*)d_in[5];
    const float* bf1 = (const float*)d_in[6];
    const float* Wf2 = (const float*)d_in[7];
    const float* bf2 = (const float*)d_in[8];
    const int* edge  = (const int*)d_in[9];
    const int* batch = (const int*)d_in[10];

    const int N = in_sizes[10];      // 100000
    const int E = in_sizes[9] / 2;   // 3200000
    const int* srcA = edge;
    const int* dstA = edge + E;
    float* out = (float*)d_out;

    const int NB = (N + 511) >> 9;   // dst buckets of 512 nodes

    char* p = (char*)d_ws;
    auto alloc = [&](size_t bytes) {
        char* r = p;
        p += (bytes + 255) & ~(size_t)255;
        return r;
    };
    float* gsum     = (float*)alloc(64 * 64 * 4);
    int*   gcnt     = (int*)alloc(64 * 4);
    int*   bcount   = (int*)alloc(256 * 4);
    int*   bfill    = (int*)alloc(256 * 4);
    size_t zbytes   = (size_t)(p - (char*)d_ws);
    int*   bstart   = (int*)alloc(260 * 4);
    float* dis      = (float*)alloc((size_t)N * 4);
    int*   rs8      = (int*)alloc(((size_t)N * 8 + 1) * 4);
    unsigned short* Wp1 = (unsigned short*)alloc(8 * 4 * 64 * 8 * 2);  // 32 KB
    unsigned short* Wp2 = (unsigned short*)alloc(8 * 2 * 64 * 8 * 2);  // 16 KB
    unsigned int* stage = (unsigned int*)alloc((size_t)E * 4);
    int*   csr_src  = (int*)alloc((size_t)E * 4);
    unsigned short* bufAb = (unsigned short*)alloc((size_t)N * 128 * 2);
    unsigned short* bufBb = (unsigned short*)alloc((size_t)N * 128 * 2);

    hipMemsetAsync(d_ws, 0, zbytes, stream);

    const int EB = (E + 4095) / 4096;
    bucket_hist_kernel<<<EB, 256, 0, stream>>>(dstA, bcount, E);
    bucket_scan_kernel<<<1, 256, 0, stream>>>(bcount, bstart, rs8, NB, N, E);
    bucket_scatter_kernel<<<EB, 256, 0, stream>>>(srcA, dstA, bstart, bfill, stage, E);
    csr_build_kernel<<<NB, 256, 0, stream>>>(stage, bstart, rs8, dis, csr_src, N);

    // weight prep for MFMA GEMMs
    wprep_kernel<128, 128><<<8, 256, 0, stream>>>(W1, Wp1);
    wprep_kernel<128, 64><<<4, 256, 0, stream>>>(W2, Wp2);

    const int GB = (N + 127) / 128;   // 4 waves x 32 rows per block
    // layer 1: h = x@W1 (fp32 in, bf16 out) ; h1 = relu(d*(sum+self) + b1)
    gemm_mfma_kernel<128, 128, true><<<GB, 256, 0, stream>>>(x, Wp1, bufAb, N);
    aggregate_kernel<128><<<(N + 3) / 4, 256, 0, stream>>>(bufAb, dis, rs8, csr_src,
                                                           b1, bufBb, N);
    // layer 2
    gemm_mfma_kernel<128, 64, false><<<GB, 256, 0, stream>>>(bufBb, Wp2, bufAb, N);
    aggregate_kernel<64><<<(N + 3) / 4, 256, 0, stream>>>(bufAb, dis, rs8, csr_src,
                                                          b2, bufBb, N);
    // head: pool(h2) then tiny GEMMs (pool(h2@Wf1+bf1) = pool(h2)@Wf1+bf1)
    pool_kernel<<<(N + 127) / 128, 64, 0, stream>>>(bufBb, batch, gsum, N);
    count_batch_kernel<<<(N + 255) / 256, 256, 0, stream>>>(batch, gcnt, N);
    head_kernel<<<64, 128, 0, stream>>>(gsum, gcnt, Wf1, bf1, Wf2, bf2, out);
}

// Round 10
// 426.327 us; speedup vs baseline: 1.5407x; 1.5407x over previous
//
#include <hip/hip_runtime.h>

// ---------------------------------------------------------------------------
// GCN forward. Weights fp32->bf16 MFMA, activations: gather buffers in FP8
// (e4m3, HW cvt), GEMM inputs/pool in bf16, accumulation fp32.
// CSR: bucketed radix (dst>>9, 512 nodes/bucket), contiguous per-node lists
// (R5 form — proven). Aggregate: R5 sub-wave gather, uint2 (8B) fp8 rows.
// Head: pool(h2) first (linearity), then tiny 64-graph GEMMs.
// ---------------------------------------------------------------------------

typedef __attribute__((ext_vector_type(8))) short bfrag;     // 8 bf16 = 4 VGPR
typedef __attribute__((ext_vector_type(16))) float f32x16;   // MFMA C/D
typedef __attribute__((ext_vector_type(2))) float floatx2;

__device__ __forceinline__ unsigned short f2bf(float f) {
    unsigned int u = __builtin_bit_cast(unsigned int, f);
    u = (u + 0x7FFFu + ((u >> 16) & 1u)) >> 16;
    return (unsigned short)u;
}
__device__ __forceinline__ float bf2f(unsigned int lo16) {
    unsigned int v = lo16 << 16;
    return __builtin_bit_cast(float, v);
}
__device__ __forceinline__ unsigned char f2fp8(float f) {
    return (unsigned char)(__builtin_amdgcn_cvt_pk_fp8_f32(f, f, 0, false) & 0xFF);
}
// 8 fp8 (uint2) -> fp32, acc += f * c   (HW packed converts, 2 vals/op)
__device__ __forceinline__ void macc8f8(float* acc, const uint2& v, float c) {
    floatx2 f0 = __builtin_amdgcn_cvt_pk_f32_fp8((int)v.x, false);
    floatx2 f1 = __builtin_amdgcn_cvt_pk_f32_fp8((int)v.x, true);
    floatx2 f2 = __builtin_amdgcn_cvt_pk_f32_fp8((int)v.y, false);
    floatx2 f3 = __builtin_amdgcn_cvt_pk_f32_fp8((int)v.y, true);
    acc[0] += f0.x * c; acc[1] += f0.y * c;
    acc[2] += f1.x * c; acc[3] += f1.y * c;
    acc[4] += f2.x * c; acc[5] += f2.y * c;
    acc[6] += f3.x * c; acc[7] += f3.y * c;
}

// --- A1: bucket histogram (bucket = dst >> 9) ---
__global__ __launch_bounds__(256) void bucket_hist_kernel(const int* __restrict__ dst,
                                                          int* __restrict__ bcount, int E) {
    __shared__ int h[256];
    int t = threadIdx.x;
    h[t] = 0;
    __syncthreads();
    int base = blockIdx.x * 4096;
#pragma unroll
    for (int i = 0; i < 16; ++i) {
        int e = base + t + i * 256;
        if (e < E) atomicAdd(&h[dst[e] >> 9], 1);
    }
    __syncthreads();
    if (h[t] > 0) atomicAdd(&bcount[t], h[t]);
}

__global__ void bucket_scan_kernel(const int* __restrict__ bcount, int* __restrict__ bstart,
                                   int* __restrict__ rowstart, int NB, int N, int E) {
    __shared__ int s[256];
    int t = threadIdx.x;
    int v = (t < NB) ? bcount[t] : 0;
    s[t] = v;
    __syncthreads();
    for (int off = 1; off < 256; off <<= 1) {
        int tmp = 0;
        if (t >= off) tmp = s[t - off];
        __syncthreads();
        s[t] += tmp;
        __syncthreads();
    }
    bstart[t] = s[t] - v;
    if (t == 255) bstart[256] = s[255];
    if (t == 0) rowstart[N] = E;
}

// --- A2: stage packed (src | local_dst<<17) into bucket windows ---
__global__ __launch_bounds__(256) void bucket_scatter_kernel(const int* __restrict__ src,
                                                             const int* __restrict__ dst,
                                                             const int* __restrict__ bstart,
                                                             int* __restrict__ bfill,
                                                             unsigned int* __restrict__ stage,
                                                             int E) {
    __shared__ int hist[256];
    __shared__ int abase[256];
    int t = threadIdx.x;
    hist[t] = 0;
    __syncthreads();
    int base = blockIdx.x * 4096;
#pragma unroll
    for (int i = 0; i < 16; ++i) {
        int e = base + t + i * 256;
        if (e < E) atomicAdd(&hist[dst[e] >> 9], 1);
    }
    __syncthreads();
    if (hist[t] > 0) {
        int r = atomicAdd(&bfill[t], hist[t]);
        abase[t] = bstart[t] + r;
    }
    __syncthreads();
    hist[t] = 0;
    __syncthreads();
#pragma unroll
    for (int i = 0; i < 16; ++i) {
        int e = base + t + i * 256;
        if (e < E) {
            int d = dst[e];
            int b = d >> 9;
            int slot = atomicAdd(&hist[b], 1);
            stage[abase[b] + slot] = (unsigned)src[e] | ((unsigned)(d & 511) << 17);
        }
    }
}

// --- B: per-bucket CSR finalize (R5 version) ---
__global__ __launch_bounds__(256) void csr_build_kernel(const unsigned int* __restrict__ stage,
                                                        const int* __restrict__ bstart,
                                                        int* __restrict__ rowstart,
                                                        float* __restrict__ dis,
                                                        int* __restrict__ csr_src, int N) {
    __shared__ int cnt[512];
    __shared__ int ofs[512];
    __shared__ int psum[256];
    int b = blockIdx.x, t = threadIdx.x;
    int node0 = b << 9;
    int nb = min(512, N - node0);
    cnt[t] = 0;
    cnt[t + 256] = 0;
    __syncthreads();
    int eb = bstart[b], ee = bstart[b + 1];
    for (int e = eb + t; e < ee; e += 256) {
        unsigned w = stage[e];
        atomicAdd(&cnt[w >> 17], 1);
    }
    __syncthreads();
    int a = cnt[2 * t], c = cnt[2 * t + 1];
    int ps = a + c;
    psum[t] = ps;
    __syncthreads();
    for (int off = 1; off < 256; off <<= 1) {
        int tmp = 0;
        if (t >= off) tmp = psum[t - off];
        __syncthreads();
        psum[t] += tmp;
        __syncthreads();
    }
    int ex = psum[t] - ps;
    ofs[2 * t] = ex;
    ofs[2 * t + 1] = ex + a;
    if (2 * t < nb) {
        rowstart[node0 + 2 * t] = eb + ex;
        dis[node0 + 2 * t] = rsqrtf(1.f + (float)a);
    }
    if (2 * t + 1 < nb) {
        rowstart[node0 + 2 * t + 1] = eb + ex + a;
        dis[node0 + 2 * t + 1] = rsqrtf(1.f + (float)c);
    }
    __syncthreads();
    for (int e = eb + t; e < ee; e += 256) {
        unsigned w = stage[e];
        int l = w >> 17;
        int slot = atomicAdd(&ofs[l], 1);
        csr_src[eb + slot] = (int)(w & 0x1FFFFu);
    }
}

// --- pack W[K][NC] fp32 -> bf16 MFMA B-frag order ---
template <int K, int NC>
__global__ __launch_bounds__(256) void wprep_kernel(const float* __restrict__ W,
                                                    unsigned short* __restrict__ Wf) {
    constexpr int CT = NC / 32, KT = K / 16;
    int idx = blockIdx.x * blockDim.x + threadIdx.x;
    if (idx >= KT * CT * 64) return;
    int l = idx & 63;
    int fi = idx >> 6;
    int ct = fi % CT, kt = fi / CT;
    int n = ct * 32 + (l & 31);
    int k0 = kt * 16 + 8 * (l >> 5);
    unsigned short v[8];
#pragma unroll
    for (int j = 0; j < 8; ++j) v[j] = f2bf(W[(size_t)(k0 + j) * NC + n]);
    uint4 o;
    o.x = (unsigned)v[0] | ((unsigned)v[1] << 16);
    o.y = (unsigned)v[2] | ((unsigned)v[3] << 16);
    o.z = (unsigned)v[4] | ((unsigned)v[5] << 16);
    o.w = (unsigned)v[6] | ((unsigned)v[7] << 16);
    *(uint4*)&Wf[(size_t)idx * 8] = o;
}

// --- MFMA GEMM: C[M][NC] = A[M][K] @ Wf(frag-packed bf16) ---
//     A fp32 (in-reg cvt) or bf16; C written fp8 (gather buffer).
template <int K, int NC, bool IN_F32>
__global__ __launch_bounds__(256) void gemm_mfma_kernel(const void* __restrict__ Av,
                                                        const unsigned short* __restrict__ Wf,
                                                        unsigned char* __restrict__ C,
                                                        int M) {
    constexpr int KT = K / 16, CT = NC / 32;
    int wid = (blockIdx.x * blockDim.x + threadIdx.x) >> 6;
    int lane = threadIdx.x & 63;
    int row0 = wid * 32;
    if (row0 >= M) return;

    bfrag B[KT][CT];
#pragma unroll
    for (int kt = 0; kt < KT; ++kt)
#pragma unroll
        for (int ct = 0; ct < CT; ++ct)
            B[kt][ct] = *(const bfrag*)&Wf[(size_t)((kt * CT + ct) * 64 + lane) * 8];

    f32x16 acc[CT];
#pragma unroll
    for (int ct = 0; ct < CT; ++ct)
#pragma unroll
        for (int i = 0; i < 16; ++i) acc[ct][i] = 0.f;

    int r = row0 + (lane & 31);
    if (r >= M) r = M - 1;
#pragma unroll
    for (int kt = 0; kt < KT; ++kt) {
        bfrag a;
        if (IN_F32) {
            const float* Arow = &((const float*)Av)[(size_t)r * K + 8 * (lane >> 5)];
            float4 v0 = *(const float4*)&Arow[kt * 16];
            float4 v1 = *(const float4*)&Arow[kt * 16 + 4];
            a[0] = (short)f2bf(v0.x); a[1] = (short)f2bf(v0.y);
            a[2] = (short)f2bf(v0.z); a[3] = (short)f2bf(v0.w);
            a[4] = (short)f2bf(v1.x); a[5] = (short)f2bf(v1.y);
            a[6] = (short)f2bf(v1.z); a[7] = (short)f2bf(v1.w);
        } else {
            const unsigned short* Arow =
                &((const unsigned short*)Av)[(size_t)r * K + 8 * (lane >> 5)];
            a = *(const bfrag*)&Arow[kt * 16];
        }
#pragma unroll
        for (int ct = 0; ct < CT; ++ct)
            acc[ct] = __builtin_amdgcn_mfma_f32_32x32x16_bf16(a, B[kt][ct], acc[ct], 0, 0, 0);
    }

    // C/D layout: col = lane&31, row = (reg&3) + 8*(reg>>2) + 4*(lane>>5)
    int colb = lane & 31;
    int rowq = 4 * (lane >> 5);
#pragma unroll
    for (int ct = 0; ct < CT; ++ct) {
        int col = ct * 32 + colb;
#pragma unroll
        for (int rg = 0; rg < 16; ++rg) {
            int row = row0 + (rg & 3) + 8 * (rg >> 2) + rowq;
            if (row < M) C[(size_t)row * NC + col] = f2fp8(acc[ct][rg]);
        }
    }
}

// --- wave-per-node gather aggregation: fp8 rows (8B/lane), fp32 accum,
//     bf16 out: out = relu(d*(sum dis_s*h_s + d*h_n) + bias)
template <int NC>
__global__ __launch_bounds__(256) void aggregate_kernel(const unsigned char* __restrict__ h,
                                                        const float* __restrict__ dis,
                                                        const int* __restrict__ rowstart,
                                                        const int* __restrict__ csr_src,
                                                        const float* __restrict__ bias,
                                                        unsigned short* __restrict__ out,
                                                        int N) {
    constexpr int LPR = NC / 8;   // lanes per row (8B = 8 fp8 each)
    constexpr int RPS = 64 / LPR; // rows (edges) per step
    int wid = (blockIdx.x * blockDim.x + threadIdx.x) >> 6;
    int lane = threadIdx.x & 63;
    if (wid >= N) return;
    int n = wid;
    int sub = lane / LPR;
    int fid = lane % LPR;
    const uint2* h8 = (const uint2*)h;   // row = LPR uint2
    float d = dis[n];
    float acc[8];
#pragma unroll
    for (int i = 0; i < 8; ++i) acc[i] = 0.f;
    if (sub == 0) {
        uint2 hv = h8[(size_t)n * LPR + fid];
        macc8f8(acc, hv, d);
    }

    int beg = rowstart[n], end = rowstart[n + 1];
    for (int e0 = beg; e0 < end; e0 += 64) {
        int idx = e0 + lane;
        int sv = 0;
        float dv = 0.f;
        if (idx < end) { sv = csr_src[idx]; dv = dis[sv]; }
        int cnt = min(64, end - e0);
        int j = 0;
        for (; j + 2 * RPS <= cnt; j += 2 * RPS) {
            int ja = j + sub, jb = j + RPS + sub;
            int sa = __shfl(sv, ja); float ca = __shfl(dv, ja);
            int sb = __shfl(sv, jb); float cb = __shfl(dv, jb);
            uint2 va = h8[(size_t)sa * LPR + fid];
            uint2 vb = h8[(size_t)sb * LPR + fid];
            macc8f8(acc, va, ca);
            macc8f8(acc, vb, cb);
        }
        for (; j < cnt; j += RPS) {
            int jj = j + sub;
            int jc = min(jj, cnt - 1);
            int s = __shfl(sv, jc);
            float c = __shfl(dv, jc);
            if (jj >= cnt) c = 0.f;
            uint2 v = h8[(size_t)s * LPR + fid];
            macc8f8(acc, v, c);
        }
    }
#pragma unroll
    for (int m = LPR; m < 64; m <<= 1) {
#pragma unroll
        for (int i = 0; i < 8; ++i) acc[i] += __shfl_xor(acc[i], m);
    }
    if (sub == 0) {
        const float4 bv0 = *(const float4*)&bias[fid * 8 + 0];
        const float4 bv1 = *(const float4*)&bias[fid * 8 + 4];
        float r[8];
        r[0] = fmaxf(acc[0] * d + bv0.x, 0.f);
        r[1] = fmaxf(acc[1] * d + bv0.y, 0.f);
        r[2] = fmaxf(acc[2] * d + bv0.z, 0.f);
        r[3] = fmaxf(acc[3] * d + bv0.w, 0.f);
        r[4] = fmaxf(acc[4] * d + bv1.x, 0.f);
        r[5] = fmaxf(acc[5] * d + bv1.y, 0.f);
        r[6] = fmaxf(acc[6] * d + bv1.z, 0.f);
        r[7] = fmaxf(acc[7] * d + bv1.w, 0.f);
        uint4 o;
        o.x = (unsigned)f2bf(r[0]) | ((unsigned)f2bf(r[1]) << 16);
        o.y = (unsigned)f2bf(r[2]) | ((unsigned)f2bf(r[3]) << 16);
        o.z = (unsigned)f2bf(r[4]) | ((unsigned)f2bf(r[5]) << 16);
        o.w = (unsigned)f2bf(r[6]) | ((unsigned)f2bf(r[7]) << 16);
        *(uint4*)&out[(size_t)n * NC + fid * 8] = o;
    }
}

// --- pool h2 (bf16, N x 64) -> gsum[64 x 64] (batch sorted) ---
__global__ __launch_bounds__(64) void pool_kernel(const unsigned short* __restrict__ h2,
                                                  const int* __restrict__ batch,
                                                  float* __restrict__ gsum, int N) {
    int f = threadIdx.x;
    int n0 = blockIdx.x * 128;
    int nend = min(n0 + 128, N);
    float acc = 0.f;
    int gcur = batch[n0];
    for (int n = n0; n < nend; ++n) {
        int g = batch[n];
        if (g != gcur) {
            atomicAdd(&gsum[gcur * 64 + f], acc);
            acc = 0.f;
            gcur = g;
        }
        acc += bf2f(h2[(size_t)n * 64 + f]);
    }
    atomicAdd(&gsum[gcur * 64 + f], acc);
}

__global__ __launch_bounds__(256) void count_batch_kernel(const int* __restrict__ batch,
                                                          int* __restrict__ gcnt, int N) {
    __shared__ int lc[64];
    int t = threadIdx.x;
    if (t < 64) lc[t] = 0;
    __syncthreads();
    int n = blockIdx.x * blockDim.x + t;
    if (n < N) atomicAdd(&lc[batch[n]], 1);
    __syncthreads();
    if (t < 64 && lc[t] > 0) atomicAdd(&gcnt[t], lc[t]);
}

// --- head: ge = pooled_h2 @ Wf1 + bf1 ; ic = ge @ Wf2 + bf2 ---
__global__ __launch_bounds__(128) void head_kernel(const float* __restrict__ gsum,
                                                   const int* __restrict__ gcnt,
                                                   const float* __restrict__ Wf1,
                                                   const float* __restrict__ bf1,
                                                   const float* __restrict__ Wf2,
                                                   const float* __restrict__ bf2,
                                                   float* __restrict__ out) {
    __shared__ float ph[64];
    __shared__ float red0[128], red1[128];
    int g = blockIdx.x, f = threadIdx.x;
    if (f < 64) ph[f] = gsum[g * 64 + f] / (float)max(gcnt[g], 1);
    __syncthreads();
    float ge = bf1[f];
#pragma unroll 8
    for (int k = 0; k < 64; ++k) ge += ph[k] * Wf1[k * 128 + f];
    out[g * 128 + f] = ge;
    red0[f] = ge * Wf2[f * 2 + 0];
    red1[f] = ge * Wf2[f * 2 + 1];
    __syncthreads();
    for (int off = 64; off > 0; off >>= 1) {
        if (f < off) { red0[f] += red0[f + off]; red1[f] += red1[f + off]; }
        __syncthreads();
    }
    if (f == 0) {
        out[8192 + 1 + g * 2 + 0] = red0[0] + bf2[0];
        out[8192 + 1 + g * 2 + 1] = red1[0] + bf2[1];
        if (g == 0) out[8192] = 0.f;
    }
}

extern "C" void kernel_launch(void* const* d_in, const int* in_sizes, int n_in,
                              void* d_out, int out_size, void* d_ws, size_t ws_size,
                              hipStream_t stream) {
    const float* x   = (const float*)d_in[0];
    const float* W1  = (const float*)d_in[1];
    const float* b1  = (const float*)d_in[2];
    const float* W2  = (const float*)d_in[3];
    const float* b2  = (const float*)d_in[4];
    const float* Wf1 = (const float*)d_in[5];
    const float* bf1 = (const float*)d_in[6];
    const float* Wf2 = (const float*)d_in[7];
    const float* bf2 = (const float*)d_in[8];
    const int* edge  = (const int*)d_in[9];
    const int* batch = (const int*)d_in[10];

    const int N = in_sizes[10];      // 100000
    const int E = in_sizes[9] / 2;   // 3200000
    const int* srcA = edge;
    const int* dstA = edge + E;
    float* out = (float*)d_out;

    const int NB = (N + 511) >> 9;   // dst buckets of 512 nodes

    char* p = (char*)d_ws;
    auto alloc = [&](size_t bytes) {
        char* r = p;
        p += (bytes + 255) & ~(size_t)255;
        return r;
    };
    float* gsum     = (float*)alloc(64 * 64 * 4);
    int*   gcnt     = (int*)alloc(64 * 4);
    int*   bcount   = (int*)alloc(256 * 4);
    int*   bfill    = (int*)alloc(256 * 4);
    size_t zbytes   = (size_t)(p - (char*)d_ws);
    int*   bstart   = (int*)alloc(260 * 4);
    float* dis      = (float*)alloc((size_t)N * 4);
    int*   rowstart = (int*)alloc((size_t)(N + 1) * 4);
    unsigned short* Wp1 = (unsigned short*)alloc(8 * 4 * 64 * 8 * 2);  // 32 KB
    unsigned short* Wp2 = (unsigned short*)alloc(8 * 2 * 64 * 8 * 2);  // 16 KB
    unsigned int* stage = (unsigned int*)alloc((size_t)E * 4);
    int*   csr_src  = (int*)alloc((size_t)E * 4);
    unsigned char*  hf8   = (unsigned char*)alloc((size_t)N * 128);      // h then g (fp8)
    unsigned short* h1b   = (unsigned short*)alloc((size_t)N * 128 * 2); // h1 (bf16)
    unsigned short* h2b   = (unsigned short*)alloc((size_t)N * 64 * 2);  // h2 (bf16)

    hipMemsetAsync(d_ws, 0, zbytes, stream);

    const int EB = (E + 4095) / 4096;
    bucket_hist_kernel<<<EB, 256, 0, stream>>>(dstA, bcount, E);
    bucket_scan_kernel<<<1, 256, 0, stream>>>(bcount, bstart, rowstart, NB, N, E);
    bucket_scatter_kernel<<<EB, 256, 0, stream>>>(srcA, dstA, bstart, bfill, stage, E);
    csr_build_kernel<<<NB, 256, 0, stream>>>(stage, bstart, rowstart, dis, csr_src, N);

    // weight prep for MFMA GEMMs
    wprep_kernel<128, 128><<<8, 256, 0, stream>>>(W1, Wp1);
    wprep_kernel<128, 64><<<4, 256, 0, stream>>>(W2, Wp2);

    const int GB = (N + 127) / 128;   // 4 waves x 32 rows per block
    // layer 1: h = x@W1 (fp32 in, fp8 out) ; h1 = relu(d*(sum+self) + b1) (bf16)
    gemm_mfma_kernel<128, 128, true><<<GB, 256, 0, stream>>>(x, Wp1, hf8, N);
    aggregate_kernel<128><<<(N + 3) / 4, 256, 0, stream>>>(hf8, dis, rowstart, csr_src,
                                                           b1, h1b, N);
    // layer 2: g = h1@W2 (bf16 in, fp8 out) ; h2 = relu(...) (bf16)
    gemm_mfma_kernel<128, 64, false><<<GB, 256, 0, stream>>>(h1b, Wp2, hf8, N);
    aggregate_kernel<64><<<(N + 3) / 4, 256, 0, stream>>>(hf8, dis, rowstart, csr_src,
                                                          b2, h2b, N);
    // head: pool(h2) then tiny GEMMs (pool(h2@Wf1+bf1) = pool(h2)@Wf1+bf1)
    pool_kernel<<<(N + 127) / 128, 64, 0, stream>>>(h2b, batch, gsum, N);
    count_batch_kernel<<<(N + 255) / 256, 256, 0, stream>>>(batch, gcnt, N);
    head_kernel<<<64, 128, 0, stream>>>(gsum, gcnt, Wf1, bf1, Wf2, bf2, out);
}